// Round 1
// baseline (581.041 us; speedup 1.0000x reference)
//
#include <hip/hip_runtime.h>

#define BS 4096
#define IN_DIM 2048
#define NFFT 16384
#define TOTAL_D 129
#define SLACK 64

#define INV_SQRT_N 0.0078125f                 // 1/128
#define SQRT2_OVER_SQRTN 0.01104854346e0f     // sqrt(2)/128
#define TWO_PI_OVER_N 3.8349519697141029e-4f  // 2*pi/16384

// ---------------------------------------------------------------------------
// Kernel 1: h = x @ W_proj^T + b_proj   (4096 x 129)
// Split-K=2 (blockIdx.y), atomicAdd into pre-zeroed h. 32 rows per block.
// ---------------------------------------------------------------------------
__global__ __launch_bounds__(256) void k_proj(const float* __restrict__ x,
                                              const float* __restrict__ W,
                                              const float* __restrict__ b,
                                              float* __restrict__ h) {
    __shared__ float xs[32][68];        // stride 68: (4r+kk) banks, conflict-free reads
    __shared__ float wt[TOTAL_D][68];
    const int tid = threadIdx.x;
    const int tx = tid & 15, ty = tid >> 4;   // tx -> cols, ty -> row pair
    const int r0 = blockIdx.x * 32;
    const int kbase0 = blockIdx.y * 1024;

    float acc[2][9];
#pragma unroll
    for (int i = 0; i < 2; ++i)
#pragma unroll
        for (int j = 0; j < 9; ++j) acc[i][j] = 0.f;

    for (int ch = 0; ch < 16; ++ch) {
        const int kb = kbase0 + ch * 64;
        // stage x tile 32x64 (512 float4, 2 per thread)
        {
            int v = tid;
#pragma unroll
            for (int rep = 0; rep < 2; ++rep, v += 256) {
                int row = v >> 4, c4 = (v & 15) << 2;
                float4 val = *(const float4*)&x[(size_t)(r0 + row) * IN_DIM + kb + c4];
                *(float4*)&xs[row][c4] = val;
            }
        }
        // stage W tile 129x64 (2064 float4)
        for (int v = tid; v < TOTAL_D * 16; v += 256) {
            int row = v >> 4, c4 = (v & 15) << 2;
            float4 val = *(const float4*)&W[(size_t)row * IN_DIM + kb + c4];
            *(float4*)&wt[row][c4] = val;
        }
        __syncthreads();
#pragma unroll 2
        for (int kk = 0; kk < 64; kk += 4) {
            float4 xa = *(const float4*)&xs[2 * ty][kk];
            float4 xb = *(const float4*)&xs[2 * ty + 1][kk];
#pragma unroll
            for (int j = 0; j < 9; ++j) {
                int c = tx + 16 * j;
                if (c < TOTAL_D) {
                    float4 wv = *(const float4*)&wt[c][kk];
                    acc[0][j] = fmaf(xa.x, wv.x, acc[0][j]);
                    acc[0][j] = fmaf(xa.y, wv.y, acc[0][j]);
                    acc[0][j] = fmaf(xa.z, wv.z, acc[0][j]);
                    acc[0][j] = fmaf(xa.w, wv.w, acc[0][j]);
                    acc[1][j] = fmaf(xb.x, wv.x, acc[1][j]);
                    acc[1][j] = fmaf(xb.y, wv.y, acc[1][j]);
                    acc[1][j] = fmaf(xb.z, wv.z, acc[1][j]);
                    acc[1][j] = fmaf(xb.w, wv.w, acc[1][j]);
                }
            }
        }
        __syncthreads();
    }
#pragma unroll
    for (int j = 0; j < 9; ++j) {
        int c = tx + 16 * j;
        if (c < TOTAL_D) {
#pragma unroll
            for (int i = 0; i < 2; ++i) {
                float v = acc[i][j];
                if (blockIdx.y == 0) v += b[c];   // bias added exactly once
                atomicAdd(&h[(size_t)(r0 + 2 * ty + i) * TOTAL_D + c], v);
            }
        }
    }
}

// ---------------------------------------------------------------------------
// Kernel 2: out[b,t] = sum_k h[b,k] * B[t,k], basis B synthesized on the fly.
//   k=0   : 1/sqrt(N)                          (handled in acc init)
//   k=2j+1: sqrt2/sqrt(N) * cos(2pi (j+1) t/N)
//   k=2j+2: sqrt2/sqrt(N) * sin(2pi (j+1) t/N)
//   k=65+s: Ws[t,s]
// Block tile 128(rows b) x 128(cols t), 8x8 per thread (split 4+4 halves so
// LDS reads are <=2-way bank aliased). K'=128 (features 1..128) in 4 chunks
// of 32: chunks 0-1 = trig, chunks 2-3 = slack.
// ---------------------------------------------------------------------------
__global__ __launch_bounds__(256, 2) void k_main(const float* __restrict__ h,
                                                 const float* __restrict__ Wsl,
                                                 float* __restrict__ out) {
    __shared__ float hsT[32][132];   // [m][r], stride 132 -> 8-way only on staging writes
    __shared__ float bsT[32][132];   // [m][t]
    const int tid = threadIdx.x;
    const int tx = tid & 15, ty = tid >> 4;
    const int c0 = blockIdx.x * 128;
    const int r0 = blockIdx.y * 128;

    float acc[2][2][4][4];  // [rowhalf][colhalf][i][j]
    // init with DC term: h[r,0] * 1/sqrt(N) (basis col 0 is constant)
#pragma unroll
    for (int ih = 0; ih < 2; ++ih) {
#pragma unroll
        for (int i = 0; i < 4; ++i) {
            int r = r0 + ih * 64 + 4 * ty + i;
            float dc = h[(size_t)r * TOTAL_D] * INV_SQRT_N;
#pragma unroll
            for (int jh = 0; jh < 2; ++jh)
#pragma unroll
                for (int j = 0; j < 4; ++j) acc[ih][jh][i][j] = dc;
        }
    }

    for (int ch = 0; ch < 4; ++ch) {
        const int mb = ch * 32;
        // stage h slice: hsT[m][r] = h[r0+r][1+mb+m]  (global-coalesced over m)
        for (int v = tid; v < 32 * 128; v += 256) {
            int m = v & 31, r = v >> 5;
            hsT[m][r] = h[(size_t)(r0 + r) * TOTAL_D + 1 + mb + m];
        }
        if (ch < 2) {
            // trig features: k' in [ch*16, ch*16+16), exact integer phase
            for (int v = tid; v < 16 * 128; v += 256) {
                int kl = v >> 7, t = v & 127;
                int f = ch * 16 + kl + 1;
                int phase = (f * (c0 + t)) & (NFFT - 1);
                float ang = (float)phase * TWO_PI_OVER_N;
                float sv, cv;
                __sincosf(ang, &sv, &cv);
                bsT[2 * kl][t]     = SQRT2_OVER_SQRTN * cv;
                bsT[2 * kl + 1][t] = SQRT2_OVER_SQRTN * sv;
            }
        } else {
            // slack features: s in [(ch-2)*32, +32)
            int sb = (ch - 2) * 32;
            for (int v = tid; v < 32 * 128; v += 256) {
                int s = v & 31, t = v >> 5;
                bsT[s][t] = Wsl[(size_t)(c0 + t) * SLACK + sb + s];
            }
        }
        __syncthreads();
#pragma unroll 4
        for (int kk = 0; kk < 32; ++kk) {
            float4 a0 = *(const float4*)&hsT[kk][4 * ty];
            float4 a1 = *(const float4*)&hsT[kk][64 + 4 * ty];
            float4 b0 = *(const float4*)&bsT[kk][4 * tx];
            float4 b1 = *(const float4*)&bsT[kk][64 + 4 * tx];
            float ar[2][4] = {{a0.x, a0.y, a0.z, a0.w}, {a1.x, a1.y, a1.z, a1.w}};
            float br[2][4] = {{b0.x, b0.y, b0.z, b0.w}, {b1.x, b1.y, b1.z, b1.w}};
#pragma unroll
            for (int ih = 0; ih < 2; ++ih)
#pragma unroll
                for (int jh = 0; jh < 2; ++jh)
#pragma unroll
                    for (int i = 0; i < 4; ++i)
#pragma unroll
                        for (int j = 0; j < 4; ++j)
                            acc[ih][jh][i][j] = fmaf(ar[ih][i], br[jh][j], acc[ih][jh][i][j]);
        }
        __syncthreads();
    }

    // epilogue: coalesced float4 stores
#pragma unroll
    for (int ih = 0; ih < 2; ++ih)
#pragma unroll
        for (int i = 0; i < 4; ++i) {
            size_t r = (size_t)(r0 + ih * 64 + 4 * ty + i);
            float* orow = out + r * NFFT + c0;
            *(float4*)&orow[4 * tx] =
                make_float4(acc[ih][0][i][0], acc[ih][0][i][1], acc[ih][0][i][2], acc[ih][0][i][3]);
            *(float4*)&orow[64 + 4 * tx] =
                make_float4(acc[ih][1][i][0], acc[ih][1][i][1], acc[ih][1][i][2], acc[ih][1][i][3]);
        }
}

extern "C" void kernel_launch(void* const* d_in, const int* in_sizes, int n_in,
                              void* d_out, int out_size, void* d_ws, size_t ws_size,
                              hipStream_t stream) {
    const float* x   = (const float*)d_in[0];
    const float* W   = (const float*)d_in[1];
    const float* b   = (const float*)d_in[2];
    const float* Wsl = (const float*)d_in[3];
    float* out = (float*)d_out;
    float* h   = (float*)d_ws;   // 4096*129 fp32 = 2.1 MB scratch

    hipMemsetAsync(h, 0, (size_t)BS * TOTAL_D * sizeof(float), stream);
    k_proj<<<dim3(BS / 32, 2), 256, 0, stream>>>(x, W, b, h);
    k_main<<<dim3(NFFT / 128, BS / 128), 256, 0, stream>>>(h, Wsl, out);
}

// Round 2
// 346.449 us; speedup vs baseline: 1.6771x; 1.6771x over previous
//
#include <hip/hip_runtime.h>

#define BS 4096
#define IN_DIM 2048
#define NFFT 16384
#define TOTAL_D 129
#define SLACK 64
#define KF 128          // GEMM feature count (DC handled separately)
#define NPROJ 160       // padded proj cols (129 -> 160 = 10 n-tiles)
#define SPLITK 4

#define INV_N_SQRT 0.0078125f            // 1/128
#define SC_PAIR 0.011048543456039804f    // sqrt(2)/128
#define TWO_PI_OVER_N 3.8349519697141029e-4f

typedef __attribute__((ext_vector_type(8))) short bf16x8;
typedef __attribute__((ext_vector_type(4))) float f32x4;

__device__ __forceinline__ ushort f2bf(float f) {
    union { float f; unsigned u; } v; v.f = f;
    unsigned r = v.u + 0x7fffu + ((v.u >> 16) & 1u);   // round-nearest-even
    return (ushort)(r >> 16);
}

// ---------------------------------------------------------------------------
// Basis: Bb[t][k] bf16, k in [0,128). k<64: pure cos/sin of f=k/2+1 (exact
// integer phase); k>=64: Ws[t][k-64]. Scales are folded into hs features.
// ---------------------------------------------------------------------------
__global__ __launch_bounds__(256) void k_basis(const float* __restrict__ Ws,
                                               ushort* __restrict__ Bb) {
    int idx = blockIdx.x * 256 + threadIdx.x;    // 16384*16 work items
    int t = idx >> 4, g = idx & 15;
    ushort r[8];
    if (g < 8) {
#pragma unroll
        for (int p = 0; p < 4; ++p) {
            int f = 4 * g + p + 1;                       // 1..32
            int phase = (f * t) & (NFFT - 1);
            float ang = (float)phase * TWO_PI_OVER_N;
            float sv, cv;
            __sincosf(ang, &sv, &cv);
            r[2 * p] = f2bf(cv);
            r[2 * p + 1] = f2bf(sv);
        }
    } else {
        const float* w = &Ws[(size_t)t * SLACK + (g - 8) * 8];
        float4 w0 = *(const float4*)w;
        float4 w1 = *(const float4*)(w + 4);
        r[0] = f2bf(w0.x); r[1] = f2bf(w0.y); r[2] = f2bf(w0.z); r[3] = f2bf(w0.w);
        r[4] = f2bf(w1.x); r[5] = f2bf(w1.y); r[6] = f2bf(w1.z); r[7] = f2bf(w1.w);
    }
    ushort4 lo = {r[0], r[1], r[2], r[3]};
    ushort4 hi = {r[4], r[5], r[6], r[7]};
    ushort* dst = &Bb[(size_t)t * KF + g * 8];
    *(ushort4*)dst = lo;
    *(ushort4*)(dst + 4) = hi;
}

// ---------------------------------------------------------------------------
// Proj GEMM: h_part[kz][b][c] = sum_{k in split kz} x[b][k] * W[min(c,128)][k]
// bf16 MFMA 16x16x32, tile 128x160, 4 waves of 64x80 (4x5 frags), BK=32.
// ---------------------------------------------------------------------------
__global__ __launch_bounds__(256, 2) void k_proj(const float* __restrict__ x,
                                                 const float* __restrict__ W,
                                                 float* __restrict__ hp) {
    __shared__ ushort As[128 * 40];   // stride 40 bf16 = 20 words: <=2-way banks
    __shared__ ushort Bs[160 * 40];
    const int tid = threadIdx.x;
    const int lane = tid & 63, wave = tid >> 6;
    const int quad = lane >> 4, m = lane & 15;
    const int wm = wave & 1, wn = wave >> 1;
    const int r0 = blockIdx.x * 128;
    const int kbase = blockIdx.y * (IN_DIM / SPLITK);

    f32x4 acc[4][5];
#pragma unroll
    for (int i = 0; i < 4; ++i)
#pragma unroll
        for (int j = 0; j < 5; ++j) acc[i][j] = 0.f;

    for (int ch = 0; ch < 16; ++ch) {
        const int kb = kbase + ch * 32;
        // stage x tile 128x32 (fp32 -> bf16)
#pragma unroll
        for (int it = 0; it < 4; ++it) {
            int v = tid + it * 256;
            int row = v >> 3, c = v & 7;
            float4 xv = *(const float4*)&x[(size_t)(r0 + row) * IN_DIM + kb + c * 4];
            ushort4 o = {f2bf(xv.x), f2bf(xv.y), f2bf(xv.z), f2bf(xv.w)};
            *(ushort4*)&As[row * 40 + c * 4] = o;
        }
        // stage W tile 160x32 (rows >=129 clamped; results discarded later)
#pragma unroll
        for (int it = 0; it < 5; ++it) {
            int v = tid + it * 256;
            int row = v >> 3, c = v & 7;
            int rw = row < TOTAL_D ? row : TOTAL_D - 1;
            float4 wv = *(const float4*)&W[(size_t)rw * IN_DIM + kb + c * 4];
            ushort4 o = {f2bf(wv.x), f2bf(wv.y), f2bf(wv.z), f2bf(wv.w)};
            *(ushort4*)&Bs[row * 40 + c * 4] = o;
        }
        __syncthreads();
        bf16x8 af[4], bfr[5];
#pragma unroll
        for (int i = 0; i < 4; ++i)
            af[i] = *(const bf16x8*)&As[(wm * 64 + i * 16 + m) * 40 + quad * 8];
#pragma unroll
        for (int j = 0; j < 5; ++j)
            bfr[j] = *(const bf16x8*)&Bs[(wn * 80 + j * 16 + m) * 40 + quad * 8];
#pragma unroll
        for (int i = 0; i < 4; ++i)
#pragma unroll
            for (int j = 0; j < 5; ++j)
                acc[i][j] = __builtin_amdgcn_mfma_f32_16x16x32_bf16(af[i], bfr[j], acc[i][j], 0, 0, 0);
        __syncthreads();
    }
    // epilogue: C/D layout col=lane&15, row=quad*4+reg
#pragma unroll
    for (int i = 0; i < 4; ++i)
#pragma unroll
        for (int reg = 0; reg < 4; ++reg) {
            int row = r0 + wm * 64 + i * 16 + quad * 4 + reg;
            float* orow = &hp[((size_t)blockIdx.y * BS + row) * NPROJ + wn * 80 + m];
#pragma unroll
            for (int j = 0; j < 5; ++j) orow[j * 16] = acc[i][j][reg];
        }
}

// ---------------------------------------------------------------------------
// Finalize: sum split-K partials + bias -> dc0 (fp32, pre-scaled by 1/128)
// and scaled bf16 features hs[b][k]  (k<64: *sqrt2/128 ; k>=64: slack as-is)
// ---------------------------------------------------------------------------
__global__ __launch_bounds__(256) void k_finalize(const float* __restrict__ hp,
                                                  const float* __restrict__ bvec,
                                                  float* __restrict__ dc0,
                                                  ushort* __restrict__ hs) {
    int b = blockIdx.x * 256 + threadIdx.x;   // 0..4095
    int g = blockIdx.y;                       // 0..16 (cols 8g..8g+7, used c<=128)
    int c0 = g * 8;
    float v[8];
#pragma unroll
    for (int e = 0; e < 8; ++e) v[e] = 0.f;
#pragma unroll
    for (int s = 0; s < SPLITK; ++s) {
        const float* p = &hp[((size_t)s * BS + b) * NPROJ + c0];
        float4 p0 = *(const float4*)p;
        float4 p1 = *(const float4*)(p + 4);
        v[0] += p0.x; v[1] += p0.y; v[2] += p0.z; v[3] += p0.w;
        v[4] += p1.x; v[5] += p1.y; v[6] += p1.z; v[7] += p1.w;
    }
#pragma unroll
    for (int e = 0; e < 8; ++e) {
        int c = c0 + e;
        if (c >= TOTAL_D) break;
        float val = v[e] + bvec[c];
        if (c == 0) {
            dc0[b] = val * INV_N_SQRT;
        } else {
            int k = c - 1;
            float sc = (k < 64) ? SC_PAIR : 1.f;
            hs[(size_t)b * KF + k] = f2bf(val * sc);
        }
    }
}

// ---------------------------------------------------------------------------
// Main GEMM: out[b][t] = dc0[b] + sum_k hs[b][k]*Bb[t][k]
// 128x128 tile, K=128 fully staged (64 KB LDS, XOR-swizzled 16B granules),
// 4 waves of 64x64 (4x4 frags of 16x16x32), one barrier per block.
// ---------------------------------------------------------------------------
__global__ __launch_bounds__(256, 2) void k_main(const ushort* __restrict__ hs,
                                                 const float* __restrict__ dc0,
                                                 const ushort* __restrict__ Bb,
                                                 float* __restrict__ out) {
    __shared__ ushort As[128 * 128];   // [row][granule g^(row&7)], 32 KB
    __shared__ ushort Bs[128 * 128];
    const int tid = threadIdx.x;
    const int lane = tid & 63, wave = tid >> 6;
    const int quad = lane >> 4, m = lane & 15;
    const int wm = wave & 1, wn = wave >> 1;
    const int c0 = blockIdx.x * 128;   // output cols t
    const int r0 = blockIdx.y * 128;   // output rows b

    // stage A (hs) and B (basis), XOR-swizzled so frag reads are <=2-way
#pragma unroll
    for (int it = 0; it < 8; ++it) {
        int v = tid + it * 256;
        int row = v >> 4, g = v & 15;
        uint4 d = *(const uint4*)&hs[((size_t)(r0 + row) << 7) + g * 8];
        *(uint4*)&As[(row << 7) + ((g ^ (row & 7)) * 8)] = d;
    }
#pragma unroll
    for (int it = 0; it < 8; ++it) {
        int v = tid + it * 256;
        int row = v >> 4, g = v & 15;
        uint4 d = *(const uint4*)&Bb[((size_t)(c0 + row) << 7) + g * 8];
        *(uint4*)&Bs[(row << 7) + ((g ^ (row & 7)) * 8)] = d;
    }

    // DC term as C-init (fp32-exact path for the big h[:,0] value)
    f32x4 acc[4][4];
#pragma unroll
    for (int i = 0; i < 4; ++i) {
        f32x4 d = *(const f32x4*)&dc0[r0 + wm * 64 + i * 16 + quad * 4];
#pragma unroll
        for (int j = 0; j < 4; ++j) acc[i][j] = d;
    }
    __syncthreads();

#pragma unroll
    for (int ks = 0; ks < 4; ++ks) {
        bf16x8 af[4], bfr[4];
#pragma unroll
        for (int i = 0; i < 4; ++i) {
            int row = wm * 64 + i * 16 + m;
            af[i] = *(const bf16x8*)&As[(row << 7) + (((ks * 4 + quad) ^ (row & 7)) * 8)];
        }
#pragma unroll
        for (int j = 0; j < 4; ++j) {
            int row = wn * 64 + j * 16 + m;
            bfr[j] = *(const bf16x8*)&Bs[(row << 7) + (((ks * 4 + quad) ^ (row & 7)) * 8)];
        }
#pragma unroll
        for (int i = 0; i < 4; ++i)
#pragma unroll
            for (int j = 0; j < 4; ++j)
                acc[i][j] = __builtin_amdgcn_mfma_f32_16x16x32_bf16(af[i], bfr[j], acc[i][j], 0, 0, 0);
    }

    // epilogue: coalesced dword stores (16 lanes = 64B segments)
#pragma unroll
    for (int i = 0; i < 4; ++i)
#pragma unroll
        for (int reg = 0; reg < 4; ++reg) {
            int row = r0 + wm * 64 + i * 16 + quad * 4 + reg;
            float* orow = out + (size_t)row * NFFT + c0 + wn * 64 + m;
#pragma unroll
            for (int j = 0; j < 4; ++j) orow[j * 16] = acc[i][j][reg];
        }
}

extern "C" void kernel_launch(void* const* d_in, const int* in_sizes, int n_in,
                              void* d_out, int out_size, void* d_ws, size_t ws_size,
                              hipStream_t stream) {
    const float* x   = (const float*)d_in[0];
    const float* W   = (const float*)d_in[1];
    const float* b   = (const float*)d_in[2];
    const float* Wsl = (const float*)d_in[3];
    float* out = (float*)d_out;

    char* ws = (char*)d_ws;
    float*  h_part = (float*)ws;                        // 4*4096*160*4 = 10.0 MB
    ushort* Bb     = (ushort*)(ws + 10485760);          // 16384*128*2  =  4.0 MB
    ushort* hs     = (ushort*)(ws + 14680064);          // 4096*128*2   =  1.0 MB
    float*  dc0    = (float*)(ws + 15728640);           // 4096*4       = 16 KB

    k_basis<<<NFFT * 16 / 256, 256, 0, stream>>>(Wsl, Bb);
    k_proj<<<dim3(BS / 128, SPLITK), 256, 0, stream>>>(x, W, h_part);
    k_finalize<<<dim3(BS / 256, 17), 256, 0, stream>>>(h_part, b, dc0, hs);
    k_main<<<dim3(NFFT / 128, BS / 128), 256, 0, stream>>>(hs, dc0, Bb, out);
}

// Round 3
// 336.016 us; speedup vs baseline: 1.7292x; 1.0310x over previous
//
#include <hip/hip_runtime.h>

#define BS 4096
#define IN_DIM 2048
#define NFFT 16384
#define TOTAL_D 129
#define SLACK 64
#define KF 128          // GEMM feature count (DC handled separately)
#define NPROJ 160       // padded proj cols (129 -> 160 = 10 n-tiles)
#define SPLITK 8

#define INV_N_SQRT 0.0078125f            // 1/128
#define SC_PAIR 0.011048543456039804f    // sqrt(2)/128
#define TWO_PI_OVER_N 3.8349519697141029e-4f

typedef __attribute__((ext_vector_type(8))) short bf16x8;
typedef __attribute__((ext_vector_type(4))) float f32x4;

__device__ __forceinline__ ushort f2bf(float f) {
    union { float f; unsigned u; } v; v.f = f;
    unsigned r = v.u + 0x7fffu + ((v.u >> 16) & 1u);   // round-nearest-even
    return (ushort)(r >> 16);
}

// ---------------------------------------------------------------------------
// Basis: Bb[t][k] bf16, k in [0,128). k<64: pure cos/sin of f=k/2+1 (exact
// integer phase); k>=64: Ws[t][k-64]. Scales folded into hs features.
// ---------------------------------------------------------------------------
__global__ __launch_bounds__(256) void k_basis(const float* __restrict__ Ws,
                                               ushort* __restrict__ Bb) {
    int idx = blockIdx.x * 256 + threadIdx.x;    // 16384*16 work items
    int t = idx >> 4, g = idx & 15;
    ushort r[8];
    if (g < 8) {
#pragma unroll
        for (int p = 0; p < 4; ++p) {
            int f = 4 * g + p + 1;                       // 1..32
            int phase = (f * t) & (NFFT - 1);
            float ang = (float)phase * TWO_PI_OVER_N;
            float sv, cv;
            __sincosf(ang, &sv, &cv);
            r[2 * p] = f2bf(cv);
            r[2 * p + 1] = f2bf(sv);
        }
    } else {
        const float* w = &Ws[(size_t)t * SLACK + (g - 8) * 8];
        float4 w0 = *(const float4*)w;
        float4 w1 = *(const float4*)(w + 4);
        r[0] = f2bf(w0.x); r[1] = f2bf(w0.y); r[2] = f2bf(w0.z); r[3] = f2bf(w0.w);
        r[4] = f2bf(w1.x); r[5] = f2bf(w1.y); r[6] = f2bf(w1.z); r[7] = f2bf(w1.w);
    }
    ushort4 lo = {r[0], r[1], r[2], r[3]};
    ushort4 hi = {r[4], r[5], r[6], r[7]};
    ushort* dst = &Bb[(size_t)t * KF + g * 8];
    *(ushort4*)dst = lo;
    *(ushort4*)(dst + 4) = hi;
}

// ---------------------------------------------------------------------------
// Proj GEMM: h_part[kz][b][c] = sum_{k in split kz} x[b][k] * W[min(c,128)][k]
// bf16 MFMA 16x16x32, tile 128x160, 4 waves of 64x80 (4x5 frags), BK=32.
// SPLITK=8 -> 256 blocks = full CU coverage.
// ---------------------------------------------------------------------------
__global__ __launch_bounds__(256, 2) void k_proj(const float* __restrict__ x,
                                                 const float* __restrict__ W,
                                                 float* __restrict__ hp) {
    __shared__ ushort As[128 * 40];   // stride 40 bf16 = 20 words: <=2-way banks
    __shared__ ushort Bs[160 * 40];
    const int tid = threadIdx.x;
    const int lane = tid & 63, wave = tid >> 6;
    const int quad = lane >> 4, m = lane & 15;
    const int wm = wave & 1, wn = wave >> 1;
    const int r0 = blockIdx.x * 128;
    const int kbase = blockIdx.y * (IN_DIM / SPLITK);

    f32x4 acc[4][5];
#pragma unroll
    for (int i = 0; i < 4; ++i)
#pragma unroll
        for (int j = 0; j < 5; ++j) acc[i][j] = 0.f;

    for (int ch = 0; ch < IN_DIM / SPLITK / 32; ++ch) {
        const int kb = kbase + ch * 32;
        // stage x tile 128x32 (fp32 -> bf16)
#pragma unroll
        for (int it = 0; it < 4; ++it) {
            int v = tid + it * 256;
            int row = v >> 3, c = v & 7;
            float4 xv = *(const float4*)&x[(size_t)(r0 + row) * IN_DIM + kb + c * 4];
            ushort4 o = {f2bf(xv.x), f2bf(xv.y), f2bf(xv.z), f2bf(xv.w)};
            *(ushort4*)&As[row * 40 + c * 4] = o;
        }
        // stage W tile 160x32 (rows >=129 clamped; results discarded later)
#pragma unroll
        for (int it = 0; it < 5; ++it) {
            int v = tid + it * 256;
            int row = v >> 3, c = v & 7;
            int rw = row < TOTAL_D ? row : TOTAL_D - 1;
            float4 wv = *(const float4*)&W[(size_t)rw * IN_DIM + kb + c * 4];
            ushort4 o = {f2bf(wv.x), f2bf(wv.y), f2bf(wv.z), f2bf(wv.w)};
            *(ushort4*)&Bs[row * 40 + c * 4] = o;
        }
        __syncthreads();
        bf16x8 af[4], bfr[5];
#pragma unroll
        for (int i = 0; i < 4; ++i)
            af[i] = *(const bf16x8*)&As[(wm * 64 + i * 16 + m) * 40 + quad * 8];
#pragma unroll
        for (int j = 0; j < 5; ++j)
            bfr[j] = *(const bf16x8*)&Bs[(wn * 80 + j * 16 + m) * 40 + quad * 8];
#pragma unroll
        for (int i = 0; i < 4; ++i)
#pragma unroll
            for (int j = 0; j < 5; ++j)
                acc[i][j] = __builtin_amdgcn_mfma_f32_16x16x32_bf16(af[i], bfr[j], acc[i][j], 0, 0, 0);
        __syncthreads();
    }
    // epilogue: C/D layout col=lane&15, row=quad*4+reg
#pragma unroll
    for (int i = 0; i < 4; ++i)
#pragma unroll
        for (int reg = 0; reg < 4; ++reg) {
            int row = r0 + wm * 64 + i * 16 + quad * 4 + reg;
            float* orow = &hp[((size_t)blockIdx.y * BS + row) * NPROJ + wn * 80 + m];
#pragma unroll
            for (int j = 0; j < 5; ++j) orow[j * 16] = acc[i][j][reg];
        }
}

// ---------------------------------------------------------------------------
// Finalize: sum split-K partials + bias -> dc0 (fp32, pre-scaled by 1/128)
// and scaled bf16 features hs[b][k]  (k<64: *sqrt2/128 ; k>=64: slack as-is)
// ---------------------------------------------------------------------------
__global__ __launch_bounds__(256) void k_finalize(const float* __restrict__ hp,
                                                  const float* __restrict__ bvec,
                                                  float* __restrict__ dc0,
                                                  ushort* __restrict__ hs) {
    int b = blockIdx.x * 256 + threadIdx.x;   // 0..4095
    int g = blockIdx.y;                       // 0..16 (cols 8g..8g+7, used c<=128)
    int c0 = g * 8;
    float v[8];
#pragma unroll
    for (int e = 0; e < 8; ++e) v[e] = 0.f;
#pragma unroll
    for (int s = 0; s < SPLITK; ++s) {
        const float* p = &hp[((size_t)s * BS + b) * NPROJ + c0];
        float4 p0 = *(const float4*)p;
        float4 p1 = *(const float4*)(p + 4);
        v[0] += p0.x; v[1] += p0.y; v[2] += p0.z; v[3] += p0.w;
        v[4] += p1.x; v[5] += p1.y; v[6] += p1.z; v[7] += p1.w;
    }
#pragma unroll
    for (int e = 0; e < 8; ++e) {
        int c = c0 + e;
        if (c >= TOTAL_D) break;
        float val = v[e] + bvec[c];
        if (c == 0) {
            dc0[b] = val * INV_N_SQRT;
        } else {
            int k = c - 1;
            float sc = (k < 64) ? SC_PAIR : 1.f;
            hs[(size_t)b * KF + k] = f2bf(val * sc);
        }
    }
}

// ---------------------------------------------------------------------------
// Main GEMM: out[b][t] = dc0[b] + sum_k hs[b][k]*Bb[t][k]
// OPERAND-SWAPPED: MFMA-M = t (basis rows), MFMA-N = b (hs rows). C/D layout
// (col=lane&15 -> b, row=quad*4+reg -> 4 CONSECUTIVE t) makes each acc f32x4
// a direct dwordx4 store; 4 quads of a quarter-wave cover a full 64B line.
// 128x128 tile, K=128 fully staged (64 KB LDS, XOR-swizzled 16B granules),
// 4 waves of 64x64 (4x4 frags of 16x16x32), one barrier per block.
// ---------------------------------------------------------------------------
__global__ __launch_bounds__(256, 2) void k_main(const ushort* __restrict__ hs,
                                                 const float* __restrict__ dc0,
                                                 const ushort* __restrict__ Bb,
                                                 float* __restrict__ out) {
    __shared__ ushort As[128 * 128];   // basis tile [t_local][k], swizzled
    __shared__ ushort Bs[128 * 128];   // hs tile    [b_local][k], swizzled
    const int tid = threadIdx.x;
    const int lane = tid & 63, wave = tid >> 6;
    const int quad = lane >> 4, m = lane & 15;
    const int wm = wave & 1, wn = wave >> 1;   // wm -> t-half, wn -> b-half
    const int t0 = blockIdx.x * 128;
    const int b0 = blockIdx.y * 128;

    // stage basis (A) and hs (B), XOR-swizzled so frag reads are <=2-way
#pragma unroll
    for (int it = 0; it < 8; ++it) {
        int v = tid + it * 256;
        int row = v >> 4, g = v & 15;
        uint4 d = *(const uint4*)&Bb[((size_t)(t0 + row) << 7) + g * 8];
        *(uint4*)&As[(row << 7) + ((g ^ (row & 7)) * 8)] = d;
    }
#pragma unroll
    for (int it = 0; it < 8; ++it) {
        int v = tid + it * 256;
        int row = v >> 4, g = v & 15;
        uint4 d = *(const uint4*)&hs[((size_t)(b0 + row) << 7) + g * 8];
        *(uint4*)&Bs[(row << 7) + ((g ^ (row & 7)) * 8)] = d;
    }

    // DC term as C-init: per-lane scalar broadcast of dc0[b]
    f32x4 acc[4][4];
#pragma unroll
    for (int j = 0; j < 4; ++j) {
        float d = dc0[b0 + wn * 64 + j * 16 + m];
#pragma unroll
        for (int i = 0; i < 4; ++i) acc[i][j] = d;
    }
    __syncthreads();

#pragma unroll
    for (int ks = 0; ks < 4; ++ks) {
        bf16x8 af[4], bfr[4];
#pragma unroll
        for (int i = 0; i < 4; ++i) {
            int row = wm * 64 + i * 16 + m;
            af[i] = *(const bf16x8*)&As[(row << 7) + (((ks * 4 + quad) ^ (row & 7)) * 8)];
        }
#pragma unroll
        for (int j = 0; j < 4; ++j) {
            int row = wn * 64 + j * 16 + m;
            bfr[j] = *(const bf16x8*)&Bs[(row << 7) + (((ks * 4 + quad) ^ (row & 7)) * 8)];
        }
#pragma unroll
        for (int i = 0; i < 4; ++i)
#pragma unroll
            for (int j = 0; j < 4; ++j)
                acc[i][j] = __builtin_amdgcn_mfma_f32_16x16x32_bf16(af[i], bfr[j], acc[i][j], 0, 0, 0);
    }

    // epilogue: 16 dwordx4 stores per thread, quads complete 64B lines
#pragma unroll
    for (int j = 0; j < 4; ++j) {
        size_t rowb = (size_t)(b0 + wn * 64 + j * 16 + m);
        float* orow = out + rowb * NFFT + t0 + wm * 64 + quad * 4;
#pragma unroll
        for (int i = 0; i < 4; ++i)
            *(f32x4*)&orow[i * 16] = acc[i][j];
    }
}

extern "C" void kernel_launch(void* const* d_in, const int* in_sizes, int n_in,
                              void* d_out, int out_size, void* d_ws, size_t ws_size,
                              hipStream_t stream) {
    const float* x   = (const float*)d_in[0];
    const float* W   = (const float*)d_in[1];
    const float* b   = (const float*)d_in[2];
    const float* Wsl = (const float*)d_in[3];
    float* out = (float*)d_out;

    char* ws = (char*)d_ws;
    float*  h_part = (float*)ws;                        // 8*4096*160*4 = 21.0 MB
    ushort* Bb     = (ushort*)(ws + 20971520);          // 16384*128*2  =  4.0 MB
    ushort* hs     = (ushort*)(ws + 25165824);          // 4096*128*2   =  1.0 MB
    float*  dc0    = (float*)(ws + 26214400);           // 4096*4       = 16 KB

    k_basis<<<NFFT * 16 / 256, 256, 0, stream>>>(Wsl, Bb);
    k_proj<<<dim3(BS / 128, SPLITK), 256, 0, stream>>>(x, W, h_part);
    k_finalize<<<dim3(BS / 256, 17), 256, 0, stream>>>(h_part, b, dc0, hs);
    k_main<<<dim3(NFFT / 128, BS / 128), 256, 0, stream>>>(hs, dc0, Bb, out);
}